// Round 3
// baseline (56.364 us; speedup 1.0000x reference)
//
#include <hip/hip_runtime.h>

// Conv2D 3x3 pad=1: x (32,64,64,64) f32 NCHW, w (128,64,3,3) OIHW, bias(128), out (32,128,64,64) f32.
// Implicit GEMM via bf16 MFMA, pipelined:
//   prep_x: NCHW f32 -> xT[n][h][w][ci] bf16
//   prep_w: OIHW f32 -> wT[co][p*64+ci] bf16 (p = kh*3+kw)
//   conv_mfma2: grid (8,32) = 256 blocks (1/CU), 512 thr = 8 waves.
//     Each block: 128co x 8h x 64w as TWO 4h iterations (stores of iter0 drain under iter1).
//     W: preloaded to 72 VGPRs once, re-written to 2x16KB LDS dbuf per plane from regs
//        -> no vmem in the K-loop -> raw barriers never drain the store queue.
//     X: 2x50.7KB LDS dbuf, XOR-swizzled; iter1 staged during iter0 (loads@p6, writes@p8).

typedef short short8 __attribute__((ext_vector_type(8)));
typedef float f32x4  __attribute__((ext_vector_type(4)));

static __device__ __forceinline__ unsigned short f2bf(float f) {
    unsigned int u = __float_as_uint(f);
    u = (u + 0x7FFFu + ((u >> 16) & 1u)) >> 16;   // RNE
    return (unsigned short)u;
}
static __device__ __forceinline__ unsigned int pk2(float lo, float hi) {
    return (unsigned int)f2bf(lo) | ((unsigned int)f2bf(hi) << 16);
}

// ---------------- prep_x: x[n][ci][h][w] f32 -> xT[n][h][w][ci] bf16 ----------------
__global__ __launch_bounds__(256)
void prep_x(const float* __restrict__ x, unsigned short* __restrict__ xT)
{
    __shared__ float T[64][65];
    const int h = blockIdx.x, n = blockIdx.y, tid = threadIdx.x;
    const size_t nbase = (size_t)n * 262144 + (size_t)h * 64;
    #pragma unroll
    for (int i = 0; i < 16; ++i) {
        int idx = tid + i * 256;           // ci*64 + w
        int ci = idx >> 6, w = idx & 63;
        T[ci][w] = x[nbase + (size_t)ci * 4096 + w];
    }
    __syncthreads();
    const int w = tid >> 2, cg = tid & 3;  // cg: ci group of 16
    unsigned int pk[8];
    #pragma unroll
    for (int k = 0; k < 8; ++k)
        pk[k] = pk2(T[cg * 16 + 2 * k][w], T[cg * 16 + 2 * k + 1][w]);
    unsigned short* dst = xT + (((size_t)n * 64 + h) * 64 + w) * 64 + cg * 16;
    uint4 a; a.x = pk[0]; a.y = pk[1]; a.z = pk[2]; a.w = pk[3];
    uint4 b; b.x = pk[4]; b.y = pk[5]; b.z = pk[6]; b.w = pk[7];
    *(uint4*)(dst)     = a;
    *(uint4*)(dst + 8) = b;
}

// ---------------- prep_w: w[co][ci][kh][kw] f32 -> wT[co][p*64+ci] bf16 ----------------
__global__ __launch_bounds__(256)
void prep_w(const float* __restrict__ w, unsigned short* __restrict__ wT)
{
    int t = blockIdx.x * 256 + threadIdx.x;
    if (t >= 128 * 576) return;
    int co = t / 576, r = t - co * 576;
    int p = r >> 6, ci = r & 63;
    wT[t] = f2bf(w[(size_t)(co * 64 + ci) * 9 + p]);
}

// ---------------- main MFMA conv ----------------
#define XBUF 50688                      // 6 rows * 66 wp * 64 ci * 2B
#define WBUF 16384                      // 128 co * 64 ci * 2B
#define TOTAL_LDS (2*XBUF + 2*WBUF)     // 134144

__global__ __launch_bounds__(512, 2)
void conv_mfma2(const unsigned short* __restrict__ xT,
                const unsigned short* __restrict__ wT,
                const float* __restrict__ bias,
                float* __restrict__ out)
{
    extern __shared__ __align__(16) char lds[];
    char* wl = lds + 2 * XBUF;          // wbuf0 @ +0, wbuf1 @ +WBUF

    const int tid  = threadIdx.x;
    const int h0   = blockIdx.x * 8;
    const int n    = blockIdx.y;
    const int wid  = tid >> 6, lane = tid & 63;
    const int wm   = wid >> 2;          // 0..1  co-half
    const int wrow = wid & 3;           // 0..3  h row within 4h sub-tile
    const int l15  = lane & 15, l4 = lane >> 4;

    const unsigned short* xTn = xT + (size_t)n * 262144;

    // ---- W preload: 18 granules of 16B into registers (held all kernel) ----
    const int co0 = tid >> 3, wg = tid & 7;
    uint4 wreg[18];
    #pragma unroll
    for (int p = 0; p < 9; ++p) {
        wreg[p*2]   = *(const uint4*)(wT + ( co0       * 576 + p*64 + wg*8));
        wreg[p*2+1] = *(const uint4*)(wT + ((co0 + 64) * 576 + p*64 + wg*8));
    }
    const int wds0 = co0*128 + ((wg ^ (co0 & 7)) * 16);
    const int wds1 = wds0 + 64*128;     // (co0+64)&7 == co0&7

    // ---- bias preload: 16 values per thread ----
    f32x4 breg[4];
    #pragma unroll
    for (int mf = 0; mf < 4; ++mf)
        breg[mf] = *(const f32x4*)(bias + wm*64 + mf*16 + l4*4);

    // ---- X(iter 0) stage: 3168 granules, guarded; XOR-swizzled LDS ----
    {
        uint4 xreg[7];
        #pragma unroll
        for (int k = 0; k < 7; ++k) {
            int gran = tid + k*512;
            if (k < 6 || tid < 96) {
                int hp = gran / 528, rem = gran - hp*528;
                int wp = rem >> 3, g = rem & 7;
                int gh = h0 + hp - 1, gw = wp - 1;
                uint4 v; v.x = v.y = v.z = v.w = 0u;
                if ((unsigned)gh < 64u && (unsigned)gw < 64u)
                    v = *(const uint4*)(xTn + ((gh*64 + gw)*64 + g*8));
                xreg[k] = v;
            }
        }
        #pragma unroll
        for (int k = 0; k < 7; ++k) {
            int gran = tid + k*512;
            if (k < 6 || tid < 96) {
                int hp = gran / 528, rem = gran - hp*528;
                int wp = rem >> 3, g = rem & 7;
                *(uint4*)(lds + (hp*66 + wp)*128 + ((g ^ (wp & 7)) * 16)) = xreg[k];
            }
        }
    }
    // ---- W(plane 0) into wbuf0 ----
    *(uint4*)(wl + wds0) = wreg[0];
    *(uint4*)(wl + wds1) = wreg[1];
    __syncthreads();

    for (int it = 0; it < 2; ++it) {
        const char* xb = lds + it * XBUF;
        f32x4 acc[4][4];
        #pragma unroll
        for (int mf = 0; mf < 4; ++mf)
            #pragma unroll
            for (int nf = 0; nf < 4; ++nf)
                acc[mf][nf] = (f32x4)0.0f;

        uint4 xreg[7];

        #pragma unroll
        for (int p = 0; p < 9; ++p) {
            const int gp = it*9 + p;
            const char* wbr = wl + ((gp & 1) ? WBUF : 0);
            char*       wbw = wl + ((gp & 1) ? 0 : WBUF);
            const int kh = p / 3, kw = p - kh*3;

            #pragma unroll
            for (int c = 0; c < 2; ++c) {
                short8 Af[4], Bf[4];
                #pragma unroll
                for (int mf = 0; mf < 4; ++mf) {
                    const int co = wm*64 + mf*16 + l15;
                    Af[mf] = *(const short8*)(wbr + co*128 + (((c*4 + l4) ^ (co & 7)) * 16));
                }
                #pragma unroll
                for (int nf = 0; nf < 4; ++nf) {
                    const int hp = wrow + kh;
                    const int wp = nf*16 + l15 + kw;
                    Bf[nf] = *(const short8*)(xb + (hp*66 + wp)*128 + (((c*4 + l4) ^ (wp & 7)) * 16));
                }
                #pragma unroll
                for (int mf = 0; mf < 4; ++mf)
                    #pragma unroll
                    for (int nf = 0; nf < 4; ++nf)
                        acc[mf][nf] = __builtin_amdgcn_mfma_f32_16x16x32_bf16(
                            Af[mf], Bf[nf], acc[mf][nf], 0, 0, 0);
            }

            if (it == 0 && p == 6) {          // issue iter-1 X loads (before stores!)
                #pragma unroll
                for (int k = 0; k < 7; ++k) {
                    int gran = tid + k*512;
                    if (k < 6 || tid < 96) {
                        int hp = gran / 528, rem = gran - hp*528;
                        int wp = rem >> 3, g = rem & 7;
                        int gh = h0 + 4 + hp - 1, gw = wp - 1;
                        uint4 v; v.x = v.y = v.z = v.w = 0u;
                        if ((unsigned)gh < 64u && (unsigned)gw < 64u)
                            v = *(const uint4*)(xTn + ((gh*64 + gw)*64 + g*8));
                        xreg[k] = v;
                    }
                }
            }

            if (p == 8) {                      // epilogue: bias + stores for this iter
                const int h = h0 + it*4 + wrow;
                #pragma unroll
                for (int mf = 0; mf < 4; ++mf) {
                    #pragma unroll
                    for (int r = 0; r < 4; ++r) {
                        const int co = wm*64 + mf*16 + l4*4 + r;
                        float* orow = out + (((size_t)n*128 + co)*64 + h)*64;
                        const float bv = breg[mf][r];
                        #pragma unroll
                        for (int nf = 0; nf < 4; ++nf)
                            orow[nf*16 + l15] = acc[mf][nf][r] + bv;
                    }
                }
            }

            if (it == 0 && p == 8) {           // write iter-1 X tile into xbuf1
                #pragma unroll
                for (int k = 0; k < 7; ++k) {
                    int gran = tid + k*512;
                    if (k < 6 || tid < 96) {
                        int hp = gran / 528, rem = gran - hp*528;
                        int wp = rem >> 3, g = rem & 7;
                        *(uint4*)(lds + XBUF + (hp*66 + wp)*128 + ((g ^ (wp & 7)) * 16)) = xreg[k];
                    }
                }
            }

            if (gp < 17) {
                const int pn = (p == 8) ? 0 : (p + 1);   // next plane's weights (regs)
                *(uint4*)(wbw + wds0) = wreg[pn*2];
                *(uint4*)(wbw + wds1) = wreg[pn*2 + 1];
                // raw barrier: LDS-visible, does NOT drain the store queue
                __builtin_amdgcn_sched_barrier(0);
                asm volatile("s_waitcnt lgkmcnt(0)" ::: "memory");
                __builtin_amdgcn_s_barrier();
                __builtin_amdgcn_sched_barrier(0);
            }
        }
    }
}

// ---------------- fp32 fallback if ws too small ----------------
__global__ __launch_bounds__(256, 4)
void conv2d_f32_tiled(const float* __restrict__ x,
                      const float* __restrict__ wgt,
                      const float* __restrict__ bias,
                      float* __restrict__ out)
{
    __shared__ float Xlds[8][10][66];
    __shared__ float Wlds[32][72];
    const int tid = threadIdx.x;
    const int co0 = blockIdx.x * 32, h0 = blockIdx.y * 8, n = blockIdx.z;
    const int tco = tid >> 6, lane = tid & 63;
    float acc[8][8];
    #pragma unroll
    for (int i = 0; i < 8; ++i)
        #pragma unroll
        for (int j = 0; j < 8; ++j) acc[i][j] = 0.0f;
    for (int cc = 0; cc < 8; ++cc) {
        const int ci0 = cc * 8;
        for (int idx = tid; idx < 8 * 10 * 66; idx += 256) {
            const int ww = idx % 66, t = idx / 66, hh = t % 10, ci = t / 10;
            const int gh = h0 + hh - 1, gw = ww - 1;
            float v = 0.0f;
            if ((unsigned)gh < 64u && (unsigned)gw < 64u)
                v = x[(((size_t)n * 64 + ci0 + ci) * 64 + gh) * 64 + gw];
            Xlds[ci][hh][ww] = v;
        }
        for (int idx = tid; idx < 32 * 72; idx += 256) {
            const int r = idx % 72, co = idx / 72;
            Wlds[co][r] = wgt[(size_t)(co0 + co) * 576 + ci0 * 9 + r];
        }
        __syncthreads();
        for (int ci = 0; ci < 8; ++ci)
            #pragma unroll
            for (int kh = 0; kh < 3; ++kh)
                #pragma unroll
                for (int kw = 0; kw < 3; ++kw) {
                    float wv[8];
                    #pragma unroll
                    for (int i = 0; i < 8; ++i) wv[i] = Wlds[tco * 8 + i][ci * 9 + kh * 3 + kw];
                    #pragma unroll
                    for (int j = 0; j < 8; ++j) {
                        const float xv = Xlds[ci][j + kh][lane + kw];
                        #pragma unroll
                        for (int i = 0; i < 8; ++i) acc[i][j] = fmaf(wv[i], xv, acc[i][j]);
                    }
                }
        __syncthreads();
    }
    #pragma unroll
    for (int i = 0; i < 8; ++i) {
        const int co = co0 + tco * 8 + i;
        const float b = bias[co];
        #pragma unroll
        for (int j = 0; j < 8; ++j)
            out[(((size_t)n * 128 + co) * 64 + (h0 + j)) * 64 + lane] = acc[i][j] + b;
    }
}

extern "C" void kernel_launch(void* const* d_in, const int* in_sizes, int n_in,
                              void* d_out, int out_size, void* d_ws, size_t ws_size,
                              hipStream_t stream)
{
    const float* x    = (const float*)d_in[0];
    const float* wgt  = (const float*)d_in[1];
    const float* bias = (const float*)d_in[2];
    float* out        = (float*)d_out;

    const size_t XT_BYTES = (size_t)32 * 64 * 64 * 64 * 2;   // 33554432
    const size_t WT_BYTES = (size_t)128 * 576 * 2;           // 147456

    if (ws_size < XT_BYTES + WT_BYTES) {
        dim3 grid(4, 8, 32);
        conv2d_f32_tiled<<<grid, 256, 0, stream>>>(x, wgt, bias, out);
        return;
    }

    unsigned short* xT = (unsigned short*)d_ws;
    unsigned short* wT = (unsigned short*)((char*)d_ws + XT_BYTES);

    (void)hipFuncSetAttribute((const void*)conv_mfma2,
                              hipFuncAttributeMaxDynamicSharedMemorySize, TOTAL_LDS);

    prep_x<<<dim3(64, 32), 256, 0, stream>>>(x, xT);
    prep_w<<<dim3((128 * 576 + 255) / 256), 256, 0, stream>>>(wgt, wT);
    conv_mfma2<<<dim3(8, 32), 512, TOTAL_LDS, stream>>>(xT, wT, bias, out);
}

// Round 4
// 44.730 us; speedup vs baseline: 1.2601x; 1.2601x over previous
//
#include <hip/hip_runtime.h>

// Conv2D 3x3 pad=1: x (32,64,64,64) f32 NCHW, w (128,64,3,3) OIHW, bias(128), out (32,128,64,64) f32.
// Implicit GEMM via bf16 MFMA:
//   prep_x: NCHW f32 -> xT[n][h][w][ci] bf16
//   prep_w: OIHW f32 -> wT[co][p*64+ci] bf16 (p = kh*3+kw)
//   conv_mfma3: 256 thr (4 waves), block tile 64co x 4h x 64w. LDS 67KB -> 2 blocks/CU,
//     grid 1024 -> prologue/epilogue/barrier tails overlap across co-resident blocks (TLP).
//     X staged once (XOR-swizzled), W per-plane 2x8KB LDS dbuf fed by 2 uint4 regs/thread.

typedef short short8 __attribute__((ext_vector_type(8)));
typedef float f32x4  __attribute__((ext_vector_type(4)));

static __device__ __forceinline__ unsigned short f2bf(float f) {
    unsigned int u = __float_as_uint(f);
    u = (u + 0x7FFFu + ((u >> 16) & 1u)) >> 16;   // RNE
    return (unsigned short)u;
}
static __device__ __forceinline__ unsigned int pk2(float lo, float hi) {
    return (unsigned int)f2bf(lo) | ((unsigned int)f2bf(hi) << 16);
}

// ---------------- prep_x: x[n][ci][h][w] f32 -> xT[n][h][w][ci] bf16 ----------------
__global__ __launch_bounds__(256)
void prep_x(const float* __restrict__ x, unsigned short* __restrict__ xT)
{
    __shared__ float T[64][65];
    const int h = blockIdx.x, n = blockIdx.y, tid = threadIdx.x;
    const size_t nbase = (size_t)n * 262144 + (size_t)h * 64;
    #pragma unroll
    for (int i = 0; i < 16; ++i) {
        int idx = tid + i * 256;           // ci*64 + w
        int ci = idx >> 6, w = idx & 63;
        T[ci][w] = x[nbase + (size_t)ci * 4096 + w];
    }
    __syncthreads();
    const int w = tid >> 2, cg = tid & 3;  // cg: ci group of 16
    unsigned int pk[8];
    #pragma unroll
    for (int k = 0; k < 8; ++k)
        pk[k] = pk2(T[cg * 16 + 2 * k][w], T[cg * 16 + 2 * k + 1][w]);
    unsigned short* dst = xT + (((size_t)n * 64 + h) * 64 + w) * 64 + cg * 16;
    uint4 a; a.x = pk[0]; a.y = pk[1]; a.z = pk[2]; a.w = pk[3];
    uint4 b; b.x = pk[4]; b.y = pk[5]; b.z = pk[6]; b.w = pk[7];
    *(uint4*)(dst)     = a;
    *(uint4*)(dst + 8) = b;
}

// ---------------- prep_w: w[co][ci][kh][kw] f32 -> wT[co][p*64+ci] bf16 ----------------
__global__ __launch_bounds__(256)
void prep_w(const float* __restrict__ w, unsigned short* __restrict__ wT)
{
    int t = blockIdx.x * 256 + threadIdx.x;
    if (t >= 128 * 576) return;
    int co = t / 576, r = t - co * 576;
    int p = r >> 6, ci = r & 63;
    wT[t] = f2bf(w[(size_t)(co * 64 + ci) * 9 + p]);
}

// ---------------- main MFMA conv ----------------
#define XBUF 50688                      // 6 rows * 66 wp * 64 ci * 2B
#define WBUF 8192                       // 64 co * 64 ci * 2B
#define TOTAL_LDS (XBUF + 2*WBUF)       // 67072 -> 2 blocks/CU

__global__ __launch_bounds__(256, 2)
void conv_mfma3(const unsigned short* __restrict__ xT,
                const unsigned short* __restrict__ wT,
                const float* __restrict__ bias,
                float* __restrict__ out)
{
    extern __shared__ __align__(16) char lds[];
    char* wl = lds + XBUF;              // W dbuf: wl+0, wl+WBUF

    const int tid  = threadIdx.x;
    const int cb   = blockIdx.x;        // co half (0..1)
    const int h0   = blockIdx.y * 4;
    const int n    = blockIdx.z;
    const int wrow = tid >> 6;          // wave id = h row within tile (0..3)
    const int lane = tid & 63;
    const int l15  = lane & 15, l4 = lane >> 4;

    const unsigned short* xTn = xT + (size_t)n * 262144;
    const unsigned short* wTb = wT + (size_t)cb * 64 * 576;

    // ---- W staging ids: thread covers (co, g) and (co+32, g) granules ----
    const int wco = tid >> 3, wg = tid & 7;
    const int wds0 = wco * 128 + ((wg ^ (wco & 7)) * 16);
    const int wds1 = wds0 + 32 * 128;                    // (co+32)&7 == co&7
    const unsigned short* wsrc0 = wTb + wco * 576 + wg * 8;
    const unsigned short* wsrc1 = wTb + (wco + 32) * 576 + wg * 8;

    // ---- bias preload ----
    f32x4 breg[4];
    #pragma unroll
    for (int mf = 0; mf < 4; ++mf)
        breg[mf] = *(const f32x4*)(bias + cb * 64 + mf * 16 + l4 * 4);

    // ---- X stage: 3168 granules of 16B (6 rows x 66 wp x 8 g), XOR-swizzled ----
    {
        uint4 xreg[13];
        #pragma unroll
        for (int k = 0; k < 13; ++k) {
            int G = tid + k * 256;
            if (k < 12 || tid < 96) {
                int hp = G / 528, rem = G - hp * 528;
                int wp = rem >> 3, g = rem & 7;
                int gh = h0 + hp - 1, gw = wp - 1;
                uint4 v; v.x = v.y = v.z = v.w = 0u;
                if ((unsigned)gh < 64u && (unsigned)gw < 64u)
                    v = *(const uint4*)(xTn + ((gh * 64 + gw) * 64 + g * 8));
                xreg[k] = v;
            }
        }
        // W plane 0 loads (issue before LDS writes)
        uint4 w0a = *(const uint4*)(wsrc0);
        uint4 w0b = *(const uint4*)(wsrc1);
        #pragma unroll
        for (int k = 0; k < 13; ++k) {
            int G = tid + k * 256;
            if (k < 12 || tid < 96) {
                int hp = G / 528, rem = G - hp * 528;
                int wp = rem >> 3, g = rem & 7;
                *(uint4*)(lds + (hp * 66 + wp) * 128 + ((g ^ (wp & 7)) * 16)) = xreg[k];
            }
        }
        *(uint4*)(wl + wds0) = w0a;
        *(uint4*)(wl + wds1) = w0b;
    }
    __syncthreads();

    f32x4 acc[4][4];
    #pragma unroll
    for (int mf = 0; mf < 4; ++mf)
        #pragma unroll
        for (int nf = 0; nf < 4; ++nf)
            acc[mf][nf] = (f32x4)0.0f;

    #pragma unroll
    for (int p = 0; p < 9; ++p) {
        const char* wbr = wl + ((p & 1) ? WBUF : 0);
        char*       wbw = wl + ((p & 1) ? 0 : WBUF);
        const int kh = p / 3, kw = p - kh * 3;

        uint4 nw0, nw1;
        if (p < 8) {                                  // prefetch next plane (regs only)
            nw0 = *(const uint4*)(wsrc0 + (p + 1) * 64);
            nw1 = *(const uint4*)(wsrc1 + (p + 1) * 64);
        }

        #pragma unroll
        for (int c = 0; c < 2; ++c) {
            short8 Af[4], Bf[4];
            #pragma unroll
            for (int mf = 0; mf < 4; ++mf) {
                const int co = mf * 16 + l15;
                Af[mf] = *(const short8*)(wbr + co * 128 + (((c * 4 + l4) ^ (co & 7)) * 16));
            }
            #pragma unroll
            for (int nf = 0; nf < 4; ++nf) {
                const int hp = wrow + kh;
                const int wp = nf * 16 + l15 + kw;
                Bf[nf] = *(const short8*)(lds + (hp * 66 + wp) * 128 + (((c * 4 + l4) ^ (wp & 7)) * 16));
            }
            #pragma unroll
            for (int mf = 0; mf < 4; ++mf)
                #pragma unroll
                for (int nf = 0; nf < 4; ++nf)
                    acc[mf][nf] = __builtin_amdgcn_mfma_f32_16x16x32_bf16(
                        Af[mf], Bf[nf], acc[mf][nf], 0, 0, 0);
        }

        if (p < 8) {
            *(uint4*)(wbw + wds0) = nw0;
            *(uint4*)(wbw + wds1) = nw1;
            __syncthreads();
        }
    }

    // ---- epilogue: bias + store (C/D: col=lane&15, row=(lane>>4)*4+reg) ----
    {
        const int h = h0 + wrow;
        #pragma unroll
        for (int mf = 0; mf < 4; ++mf) {
            #pragma unroll
            for (int r = 0; r < 4; ++r) {
                const int co = cb * 64 + mf * 16 + l4 * 4 + r;
                float* orow = out + (((size_t)n * 128 + co) * 64 + h) * 64;
                const float bv = breg[mf][r];
                #pragma unroll
                for (int nf = 0; nf < 4; ++nf)
                    orow[nf * 16 + l15] = acc[mf][nf][r] + bv;
            }
        }
    }
}

// ---------------- fp32 fallback if ws too small ----------------
__global__ __launch_bounds__(256, 4)
void conv2d_f32_tiled(const float* __restrict__ x,
                      const float* __restrict__ wgt,
                      const float* __restrict__ bias,
                      float* __restrict__ out)
{
    __shared__ float Xlds[8][10][66];
    __shared__ float Wlds[32][72];
    const int tid = threadIdx.x;
    const int co0 = blockIdx.x * 32, h0 = blockIdx.y * 8, n = blockIdx.z;
    const int tco = tid >> 6, lane = tid & 63;
    float acc[8][8];
    #pragma unroll
    for (int i = 0; i < 8; ++i)
        #pragma unroll
        for (int j = 0; j < 8; ++j) acc[i][j] = 0.0f;
    for (int cc = 0; cc < 8; ++cc) {
        const int ci0 = cc * 8;
        for (int idx = tid; idx < 8 * 10 * 66; idx += 256) {
            const int ww = idx % 66, t = idx / 66, hh = t % 10, ci = t / 10;
            const int gh = h0 + hh - 1, gw = ww - 1;
            float v = 0.0f;
            if ((unsigned)gh < 64u && (unsigned)gw < 64u)
                v = x[(((size_t)n * 64 + ci0 + ci) * 64 + gh) * 64 + gw];
            Xlds[ci][hh][ww] = v;
        }
        for (int idx = tid; idx < 32 * 72; idx += 256) {
            const int r = idx % 72, co = idx / 72;
            Wlds[co][r] = wgt[(size_t)(co0 + co) * 576 + ci0 * 9 + r];
        }
        __syncthreads();
        for (int ci = 0; ci < 8; ++ci)
            #pragma unroll
            for (int kh = 0; kh < 3; ++kh)
                #pragma unroll
                for (int kw = 0; kw < 3; ++kw) {
                    float wv[8];
                    #pragma unroll
                    for (int i = 0; i < 8; ++i) wv[i] = Wlds[tco * 8 + i][ci * 9 + kh * 3 + kw];
                    #pragma unroll
                    for (int j = 0; j < 8; ++j) {
                        const float xv = Xlds[ci][j + kh][lane + kw];
                        #pragma unroll
                        for (int i = 0; i < 8; ++i) acc[i][j] = fmaf(wv[i], xv, acc[i][j]);
                    }
                }
        __syncthreads();
    }
    #pragma unroll
    for (int i = 0; i < 8; ++i) {
        const int co = co0 + tco * 8 + i;
        const float b = bias[co];
        #pragma unroll
        for (int j = 0; j < 8; ++j)
            out[(((size_t)n * 128 + co) * 64 + (h0 + j)) * 64 + lane] = acc[i][j] + b;
    }
}

extern "C" void kernel_launch(void* const* d_in, const int* in_sizes, int n_in,
                              void* d_out, int out_size, void* d_ws, size_t ws_size,
                              hipStream_t stream)
{
    const float* x    = (const float*)d_in[0];
    const float* wgt  = (const float*)d_in[1];
    const float* bias = (const float*)d_in[2];
    float* out        = (float*)d_out;

    const size_t XT_BYTES = (size_t)32 * 64 * 64 * 64 * 2;   // 33554432
    const size_t WT_BYTES = (size_t)128 * 576 * 2;           // 147456

    if (ws_size < XT_BYTES + WT_BYTES) {
        dim3 grid(4, 8, 32);
        conv2d_f32_tiled<<<grid, 256, 0, stream>>>(x, wgt, bias, out);
        return;
    }

    unsigned short* xT = (unsigned short*)d_ws;
    unsigned short* wT = (unsigned short*)((char*)d_ws + XT_BYTES);

    (void)hipFuncSetAttribute((const void*)conv_mfma3,
                              hipFuncAttributeMaxDynamicSharedMemorySize, TOTAL_LDS);

    prep_x<<<dim3(64, 32), 256, 0, stream>>>(x, xT);
    prep_w<<<dim3((128 * 576 + 255) / 256), 256, 0, stream>>>(wgt, wT);
    conv_mfma3<<<dim3(2, 16, 32), 256, TOTAL_LDS, stream>>>(xT, wT, bias, out);
}